// Round 7
// baseline (71.137 us; speedup 1.0000x reference)
//
#include <hip/hip_runtime.h>
#include <math.h>

#define LAMBDA_DECAY 0.01f
#define ALPHA 0.95f
#define LN_EPS 1e-5f

// Geometry (reference: M=8192, D=4096).
#define NB 512       // K1 blocks
#define RPB 16       // rows per block = M/NB
#define WPB 8        // waves per block (512 threads); wave owns D/8 = 512 cols
#define BATCH 4      // rows per barrier in K1
#define NBATCH 4     // RPB/BATCH
#define G2 64        // partials per K2 block
#define NP2 8        // NB/G2

typedef float v4f __attribute__((ext_vector_type(4)));

static __device__ __forceinline__ float wave_sum_all(float v) {
#pragma unroll
    for (int o = 32; o > 0; o >>= 1) v += __shfl_xor(v, o);
    return v;
}

static __device__ float block_sum(float v, float* sh, int nwaves) {
    int lane = threadIdx.x & 63;
    int w = threadIdx.x >> 6;
    v = wave_sum_all(v);
    if (lane == 0) sh[w] = v;
    __syncthreads();
    float r = 0.0f;
    for (int i = 0; i < nwaves; ++i) r += sh[i];
    __syncthreads();
    return r;
}

// K1: single pass over states. 8 waves/block; wave owns a 512-float D-slice
// (2 float4/lane). Rows processed in batches of 4 per barrier:
//   prefetch next batch (8 loads/lane in flight) -> 4 partial dots ->
//   lane0 writes 4 floats to double-buffered LDS -> ONE barrier ->
//   broadcast-read 8x4 partials -> 4 exp -> 4 acc updates.
// Barriers: 16 -> 4 per block. ~110 VGPR, 4 waves/SIMD (grid-limited).
// states loads are nontemporal: streamed exactly once, keep L2 for partial.
__global__ __launch_bounds__(512, 4) void fused_kernel(
    const float* __restrict__ states, const float* __restrict__ cur,
    const float* __restrict__ weights, const float* __restrict__ ts,
    const float* __restrict__ t_new,
    float* __restrict__ partial, float* __restrict__ partE, float* __restrict__ partS,
    int M, int D, float scale)
{
    __shared__ float shp[2][BATCH][WPB];

    const int wid = threadIdx.x >> 6;
    const int lane = threadIdx.x & 63;
    const int r0 = blockIdx.x * RPB;
    const int f4base = wid * 128 + lane;     // float4 index of lane's first elem
    const int rstride = D >> 2;              // row stride in float4 (1024)

    const float tn = t_new[0];

    const v4f* c4 = (const v4f*)cur;
    const v4f curp0 = c4[f4base];
    const v4f curp1 = c4[f4base + 64];

    v4f acc0 = (v4f)(0.0f), acc1 = (v4f)(0.0f);
    float E = 0.0f, S = 0.0f;

    const v4f* sp = (const v4f*)states + (size_t)r0 * rstride + f4base;

    v4f rv[2][BATCH][2];
#pragma unroll
    for (int r = 0; r < BATCH; ++r) {
        rv[0][r][0] = __builtin_nontemporal_load(&sp[(size_t)r * rstride]);
        rv[0][r][1] = __builtin_nontemporal_load(&sp[(size_t)r * rstride + 64]);
    }

#pragma unroll
    for (int b = 0; b < NBATCH; ++b) {
        const int cb = b & 1;        // compile-time after full unroll
        const int nbuf = cb ^ 1;

        // Prefetch next batch: 8 loads/lane in flight under this batch's compute.
        if (b + 1 < NBATCH) {
#pragma unroll
            for (int r = 0; r < BATCH; ++r) {
                const size_t off = (size_t)((b + 1) * BATCH + r) * rstride;
                rv[nbuf][r][0] = __builtin_nontemporal_load(&sp[off]);
                rv[nbuf][r][1] = __builtin_nontemporal_load(&sp[off + 64]);
            }
        }

        // Partial dots for the 4 current rows (independent chains).
        float pd[BATCH];
#pragma unroll
        for (int r = 0; r < BATCH; ++r) {
            const v4f a0 = rv[cb][r][0], a1 = rv[cb][r][1];
            float d0 = 0.0f, d1 = 0.0f;
            d0 = fmaf(a0[0], curp0[0], d0); d1 = fmaf(a1[0], curp1[0], d1);
            d0 = fmaf(a0[1], curp0[1], d0); d1 = fmaf(a1[1], curp1[1], d1);
            d0 = fmaf(a0[2], curp0[2], d0); d1 = fmaf(a1[2], curp1[2], d1);
            d0 = fmaf(a0[3], curp0[3], d0); d1 = fmaf(a1[3], curp1[3], d1);
            pd[r] = wave_sum_all(d0 + d1);
        }

        if (lane == 0) {
#pragma unroll
            for (int r = 0; r < BATCH; ++r) shp[cb][r][wid] = pd[r];
        }
        __syncthreads();

#pragma unroll
        for (int r = 0; r < BATCH; ++r) {
            float s = 0.0f;
#pragma unroll
            for (int w = 0; w < WPB; ++w) s += shp[cb][r][w];   // broadcast reads
            s *= scale;

            const int row = r0 + b * BATCH + r;
            const float e = expf(s);
            const float wgt = weights[row] * expf(-LAMBDA_DECAY * fabsf(tn - ts[row]));
            const float p = e * wgt;
            E += e; S += p;                  // uniform across threads

            acc0 += p * rv[cb][r][0];
            acc1 += p * rv[cb][r][1];
        }
    }

    v4f* pb = (v4f*)(partial + (size_t)blockIdx.x * D);
    pb[f4base] = acc0;
    pb[f4base + 64] = acc1;
    if (threadIdx.x == 0) {
        partE[blockIdx.x] = E;
        partS[blockIdx.x] = S;
    }
}

// K2: tree-reduce partials NB -> NP2 per column. grid=(D/256, NP2).
__global__ __launch_bounds__(256) void reduce_kernel(
    const float* __restrict__ partial, float* __restrict__ partial2, int D)
{
    const int col = blockIdx.x * 256 + threadIdx.x;
    const int b0 = blockIdx.y * G2;
    float a0 = 0.0f, a1 = 0.0f, a2 = 0.0f, a3 = 0.0f;
    for (int b = 0; b < G2; b += 4) {
        a0 += partial[(size_t)(b0 + b) * D + col];
        a1 += partial[(size_t)(b0 + b + 1) * D + col];
        a2 += partial[(size_t)(b0 + b + 2) * D + col];
        a3 += partial[(size_t)(b0 + b + 3) * D + col];
    }
    partial2[(size_t)blockIdx.y * D + col] = (a0 + a1) + (a2 + a3);
}

// K3: final NP2-way column sum + E/S reduce -> inv; blend; LayerNorm. 1 block.
__global__ __launch_bounds__(1024) void finalize_kernel(
    const float* __restrict__ partial2, const float* __restrict__ partE,
    const float* __restrict__ partS, const float* __restrict__ cur,
    float* __restrict__ out, int D)
{
    __shared__ float sh[16];
    const int tid = threadIdx.x;

    float E = 0.0f, S = 0.0f;
    for (int i = tid; i < NB; i += 1024) { E += partE[i]; S += partS[i]; }
    E = block_sum(E, sh, 16);
    S = block_sum(S, sh, 16);
    const float inv = 1.0f / (S + 1e-9f * E);

    float v[4];
    float s = 0.0f, s2 = 0.0f;
#pragma unroll
    for (int k = 0; k < 4; ++k) {
        const int c = tid + k * 1024;
        float a = 0.0f;
#pragma unroll
        for (int y = 0; y < NP2; ++y) a += partial2[y * D + c];
        const float nv = ALPHA * cur[c] + (1.0f - ALPHA) * (a * inv);
        v[k] = nv;
        s += nv; s2 += nv * nv;
    }
    s = block_sum(s, sh, 16);
    s2 = block_sum(s2, sh, 16);
    const float mean = s / (float)D;
    const float var = s2 / (float)D - mean * mean;
    const float rstd = 1.0f / sqrtf(var + LN_EPS);
#pragma unroll
    for (int k = 0; k < 4; ++k)
        out[tid + k * 1024] = (v[k] - mean) * rstd;
}

extern "C" void kernel_launch(void* const* d_in, const int* in_sizes, int n_in,
                              void* d_out, int out_size, void* d_ws, size_t ws_size,
                              hipStream_t stream) {
    const float* states     = (const float*)d_in[0];
    const float* weights    = (const float*)d_in[1];
    const float* timestamps = (const float*)d_in[2];
    const float* current    = (const float*)d_in[3];
    // d_in[4] = sensed_state: not used in the output math.
    const float* t_new      = (const float*)d_in[5];
    float* out = (float*)d_out;

    const int M = in_sizes[1];   // 8192
    const int D = in_sizes[3];   // 4096

    float* ws       = (float*)d_ws;
    float* partial  = ws;                              // [NB * D] (8 MiB)
    float* partial2 = partial + (size_t)NB * D;        // [NP2 * D]
    float* partE    = partial2 + (size_t)NP2 * D;      // [NB]
    float* partS    = partE + NB;                      // [NB]

    const float scale = 1.0f / sqrtf((float)D);

    fused_kernel<<<NB, 512, 0, stream>>>(
        states, current, weights, timestamps, t_new,
        partial, partE, partS, M, D, scale);

    {
        dim3 grid(D / 256, NP2);   // (16, 8)
        reduce_kernel<<<grid, 256, 0, stream>>>(partial, partial2, D);
    }

    finalize_kernel<<<1, 1024, 0, stream>>>(partial2, partE, partS, current, out, D);
}

// Round 8
// 43.021 us; speedup vs baseline: 1.6535x; 1.6535x over previous
//
#include <hip/hip_runtime.h>
#include <math.h>

#define LAMBDA_DECAY 0.01f
#define ALPHA 0.95f
#define LN_EPS 1e-5f

// Geometry (reference: M=8192, D=4096).
#define NB 512       // K1 blocks
#define RPB 16       // rows per block = M/NB
#define WPB 8        // waves per block (512 threads); wave owns D/8 = 512 cols
#define G2 64        // partials per K2 block
#define NP2 8        // NB/G2

typedef float v4f __attribute__((ext_vector_type(4)));

static __device__ __forceinline__ float wave_sum_all(float v) {
#pragma unroll
    for (int o = 32; o > 0; o >>= 1) v += __shfl_xor(v, o);
    return v;
}

static __device__ float block_sum(float v, float* sh, int nwaves) {
    int lane = threadIdx.x & 63;
    int w = threadIdx.x >> 6;
    v = wave_sum_all(v);
    if (lane == 0) sh[w] = v;
    __syncthreads();
    float r = 0.0f;
    for (int i = 0; i < nwaves; ++i) r += sh[i];
    __syncthreads();
    return r;
}

// K1: single pass over states. 8 waves/block; wave owns a 512-float D-slice
// (2 float4/lane). Per row: prefetch next row's slice, partial dot,
// shuffle-reduce, exchange 8 partials via double-buffered LDS.
// KEY CHANGE vs R6: the per-row exchange uses s_waitcnt lgkmcnt(0) +
// raw s_barrier instead of __syncthreads(). __syncthreads drains vmcnt(0),
// which killed the next-row prefetch every row (bare HBM latency 16x/block).
// lgkmcnt(0) orders only the ds_write of the dot partials; the prefetched
// global loads stay in flight across the barrier (counted-vmcnt idiom, T4).
// Race-safety: shp is double-buffered — a wave must pass TWO barriers before
// rewriting a buffer another wave may still be reading.
__global__ __launch_bounds__(512) void fused_kernel(
    const float* __restrict__ states, const float* __restrict__ cur,
    const float* __restrict__ weights, const float* __restrict__ ts,
    const float* __restrict__ t_new,
    float* __restrict__ partial, float* __restrict__ partE, float* __restrict__ partS,
    int M, int D, float scale)
{
    __shared__ float shp[2][WPB];

    const int wid = threadIdx.x >> 6;
    const int lane = threadIdx.x & 63;
    const int r0 = blockIdx.x * RPB;
    const int f4base = wid * 128 + lane;     // float4 index of lane's first elem
    const int rstride = D >> 2;              // row stride in float4 (1024)

    const float tn = t_new[0];

    const v4f* c4 = (const v4f*)cur;
    const v4f curp0 = c4[f4base];
    const v4f curp1 = c4[f4base + 64];

    v4f acc0 = (v4f)(0.0f), acc1 = (v4f)(0.0f);
    float E = 0.0f, S = 0.0f;

    const v4f* sp = (const v4f*)states;

    v4f rv[2][2];
    rv[0][0] = sp[(size_t)r0 * rstride + f4base];
    rv[0][1] = sp[(size_t)r0 * rstride + f4base + 64];

#pragma unroll
    for (int r = 0; r < RPB; ++r) {
        const int row = r0 + r;
        const int cb = r & 1;        // compile-time after full unroll
        const int nb = cb ^ 1;

        // Prefetch next row: stays in flight across the barrier below.
        if (r + 1 < RPB) {
            rv[nb][0] = sp[(size_t)(row + 1) * rstride + f4base];
            rv[nb][1] = sp[(size_t)(row + 1) * rstride + f4base + 64];
        }

        const v4f a0 = rv[cb][0], a1 = rv[cb][1];

        float d0 = 0.0f, d1 = 0.0f;
        d0 = fmaf(a0[0], curp0[0], d0); d1 = fmaf(a1[0], curp1[0], d1);
        d0 = fmaf(a0[1], curp0[1], d0); d1 = fmaf(a1[1], curp1[1], d1);
        d0 = fmaf(a0[2], curp0[2], d0); d1 = fmaf(a1[2], curp1[2], d1);
        d0 = fmaf(a0[3], curp0[3], d0); d1 = fmaf(a1[3], curp1[3], d1);
        float pd = wave_sum_all(d0 + d1);

        if (lane == 0) shp[cb][wid] = pd;
        // Order the ds_write only; do NOT drain vmcnt (prefetch in flight).
        asm volatile("s_waitcnt lgkmcnt(0)" ::: "memory");
        __builtin_amdgcn_s_barrier();

        float s = 0.0f;
#pragma unroll
        for (int w = 0; w < WPB; ++w) s += shp[cb][w];   // same addr: broadcast
        s *= scale;

        const float e = expf(s);
        const float wgt = weights[row] * expf(-LAMBDA_DECAY * fabsf(tn - ts[row]));
        const float p = e * wgt;
        E += e; S += p;                                   // uniform across threads

        acc0 += p * a0;
        acc1 += p * a1;
    }

    v4f* pb = (v4f*)(partial + (size_t)blockIdx.x * D);
    pb[f4base] = acc0;
    pb[f4base + 64] = acc1;
    if (threadIdx.x == 0) {
        partE[blockIdx.x] = E;
        partS[blockIdx.x] = S;
    }
}

// K2: tree-reduce partials NB -> NP2 per column. grid=(D/256, NP2).
__global__ __launch_bounds__(256) void reduce_kernel(
    const float* __restrict__ partial, float* __restrict__ partial2, int D)
{
    const int col = blockIdx.x * 256 + threadIdx.x;
    const int b0 = blockIdx.y * G2;
    float a0 = 0.0f, a1 = 0.0f, a2 = 0.0f, a3 = 0.0f;
    for (int b = 0; b < G2; b += 4) {
        a0 += partial[(size_t)(b0 + b) * D + col];
        a1 += partial[(size_t)(b0 + b + 1) * D + col];
        a2 += partial[(size_t)(b0 + b + 2) * D + col];
        a3 += partial[(size_t)(b0 + b + 3) * D + col];
    }
    partial2[(size_t)blockIdx.y * D + col] = (a0 + a1) + (a2 + a3);
}

// K3: final NP2-way column sum + E/S reduce -> inv; blend; LayerNorm. 1 block.
__global__ __launch_bounds__(1024) void finalize_kernel(
    const float* __restrict__ partial2, const float* __restrict__ partE,
    const float* __restrict__ partS, const float* __restrict__ cur,
    float* __restrict__ out, int D)
{
    __shared__ float sh[16];
    const int tid = threadIdx.x;

    float E = 0.0f, S = 0.0f;
    for (int i = tid; i < NB; i += 1024) { E += partE[i]; S += partS[i]; }
    E = block_sum(E, sh, 16);
    S = block_sum(S, sh, 16);
    const float inv = 1.0f / (S + 1e-9f * E);

    float v[4];
    float s = 0.0f, s2 = 0.0f;
#pragma unroll
    for (int k = 0; k < 4; ++k) {
        const int c = tid + k * 1024;
        float a = 0.0f;
#pragma unroll
        for (int y = 0; y < NP2; ++y) a += partial2[y * D + c];
        const float nv = ALPHA * cur[c] + (1.0f - ALPHA) * (a * inv);
        v[k] = nv;
        s += nv; s2 += nv * nv;
    }
    s = block_sum(s, sh, 16);
    s2 = block_sum(s2, sh, 16);
    const float mean = s / (float)D;
    const float var = s2 / (float)D - mean * mean;
    const float rstd = 1.0f / sqrtf(var + LN_EPS);
#pragma unroll
    for (int k = 0; k < 4; ++k)
        out[tid + k * 1024] = (v[k] - mean) * rstd;
}

extern "C" void kernel_launch(void* const* d_in, const int* in_sizes, int n_in,
                              void* d_out, int out_size, void* d_ws, size_t ws_size,
                              hipStream_t stream) {
    const float* states     = (const float*)d_in[0];
    const float* weights    = (const float*)d_in[1];
    const float* timestamps = (const float*)d_in[2];
    const float* current    = (const float*)d_in[3];
    // d_in[4] = sensed_state: not used in the output math.
    const float* t_new      = (const float*)d_in[5];
    float* out = (float*)d_out;

    const int M = in_sizes[1];   // 8192
    const int D = in_sizes[3];   // 4096

    float* ws       = (float*)d_ws;
    float* partial  = ws;                              // [NB * D] (8 MiB)
    float* partial2 = partial + (size_t)NB * D;        // [NP2 * D]
    float* partE    = partial2 + (size_t)NP2 * D;      // [NB]
    float* partS    = partE + NB;                      // [NB]

    const float scale = 1.0f / sqrtf((float)D);

    fused_kernel<<<NB, 512, 0, stream>>>(
        states, current, weights, timestamps, t_new,
        partial, partE, partS, M, D, scale);

    {
        dim3 grid(D / 256, NP2);   // (16, 8)
        reduce_kernel<<<grid, 256, 0, stream>>>(partial, partial2, D);
    }

    finalize_kernel<<<1, 1024, 0, stream>>>(partial2, partE, partS, current, out, D);
}

// Round 9
// 39.607 us; speedup vs baseline: 1.7961x; 1.0862x over previous
//
#include <hip/hip_runtime.h>
#include <math.h>

#define LAMBDA_DECAY 0.01f
#define ALPHA 0.95f
#define LN_EPS 1e-5f

// Geometry (reference: M=8192, D=4096).
#define NB 512       // K1 blocks
#define RPB 16       // rows per block = M/NB
#define WPB 8        // waves per block (512 threads); wave owns D/8 = 512 cols
#define K2Y 32       // K2 grid.y: each K2 block sums NB/K2Y = 16 partials

typedef float v4f __attribute__((ext_vector_type(4)));

static __device__ __forceinline__ float wave_sum_all(float v) {
#pragma unroll
    for (int o = 32; o > 0; o >>= 1) v += __shfl_xor(v, o);
    return v;
}

static __device__ float block_sum(float v, float* sh, int nwaves) {
    int lane = threadIdx.x & 63;
    int w = threadIdx.x >> 6;
    v = wave_sum_all(v);
    if (lane == 0) sh[w] = v;
    __syncthreads();
    float r = 0.0f;
    for (int i = 0; i < nwaves; ++i) r += sh[i];
    __syncthreads();
    return r;
}

// K1: single pass over states — EXACT R6 structure (best so far, 37.2us).
// 8 waves/block; wave owns a 512-float D-slice (2 float4/lane). Per row:
// prefetch next row's slice, partial dot, shuffle-reduce, exchange 8
// partials via double-buffered LDS with __syncthreads (R7's counted-barrier
// variant regressed: asm memory clobber cost > vmcnt-drain cost).
__global__ __launch_bounds__(512) void fused_kernel(
    const float* __restrict__ states, const float* __restrict__ cur,
    const float* __restrict__ weights, const float* __restrict__ ts,
    const float* __restrict__ t_new,
    float* __restrict__ partial, float* __restrict__ partE, float* __restrict__ partS,
    int M, int D, float scale)
{
    __shared__ float shp[2][WPB];

    const int wid = threadIdx.x >> 6;
    const int lane = threadIdx.x & 63;
    const int r0 = blockIdx.x * RPB;
    const int f4base = wid * 128 + lane;     // float4 index of lane's first elem
    const int rstride = D >> 2;              // row stride in float4 (1024)

    const float tn = t_new[0];

    const v4f* c4 = (const v4f*)cur;
    const v4f curp0 = c4[f4base];
    const v4f curp1 = c4[f4base + 64];

    v4f acc0 = (v4f)(0.0f), acc1 = (v4f)(0.0f);
    float E = 0.0f, S = 0.0f;

    const v4f* sp = (const v4f*)states;

    v4f rv[2][2];
    rv[0][0] = sp[(size_t)r0 * rstride + f4base];
    rv[0][1] = sp[(size_t)r0 * rstride + f4base + 64];

#pragma unroll
    for (int r = 0; r < RPB; ++r) {
        const int row = r0 + r;
        const int cb = r & 1;        // compile-time after full unroll
        const int nb = cb ^ 1;

        // Prefetch next row.
        if (r + 1 < RPB) {
            rv[nb][0] = sp[(size_t)(row + 1) * rstride + f4base];
            rv[nb][1] = sp[(size_t)(row + 1) * rstride + f4base + 64];
        }

        const v4f a0 = rv[cb][0], a1 = rv[cb][1];

        float d0 = 0.0f, d1 = 0.0f;
        d0 = fmaf(a0[0], curp0[0], d0); d1 = fmaf(a1[0], curp1[0], d1);
        d0 = fmaf(a0[1], curp0[1], d0); d1 = fmaf(a1[1], curp1[1], d1);
        d0 = fmaf(a0[2], curp0[2], d0); d1 = fmaf(a1[2], curp1[2], d1);
        d0 = fmaf(a0[3], curp0[3], d0); d1 = fmaf(a1[3], curp1[3], d1);
        float pd = wave_sum_all(d0 + d1);

        if (lane == 0) shp[cb][wid] = pd;
        __syncthreads();

        float s = 0.0f;
#pragma unroll
        for (int w = 0; w < WPB; ++w) s += shp[cb][w];   // same addr: broadcast
        s *= scale;

        const float e = expf(s);
        const float wgt = weights[row] * expf(-LAMBDA_DECAY * fabsf(tn - ts[row]));
        const float p = e * wgt;
        E += e; S += p;                                   // uniform across threads

        acc0 += p * a0;
        acc1 += p * a1;
    }

    v4f* pb = (v4f*)(partial + (size_t)blockIdx.x * D);
    pb[f4base] = acc0;
    pb[f4base + 64] = acc1;
    if (threadIdx.x == 0) {
        partE[blockIdx.x] = E;
        partS[blockIdx.x] = S;
    }
}

// K2: column-reduce partials straight into attn_raw[D] via atomicAdd.
// grid = (D/256, K2Y); block (by) sums partial rows by*16 .. by*16+15.
// 512 blocks * 256 adds = 131K atomics over 4096 addresses (32/address).
// attn_raw is zeroed by hipMemsetAsync before K1.
__global__ __launch_bounds__(256) void reduce_kernel(
    const float* __restrict__ partial, float* __restrict__ attn_raw, int D)
{
    const int col = blockIdx.x * 256 + threadIdx.x;
    const int b0 = blockIdx.y * (NB / K2Y);
    float a0 = 0.0f, a1 = 0.0f, a2 = 0.0f, a3 = 0.0f;
#pragma unroll
    for (int b = 0; b < NB / K2Y; b += 4) {
        a0 += partial[(size_t)(b0 + b) * D + col];
        a1 += partial[(size_t)(b0 + b + 1) * D + col];
        a2 += partial[(size_t)(b0 + b + 2) * D + col];
        a3 += partial[(size_t)(b0 + b + 3) * D + col];
    }
    atomicAdd(&attn_raw[col], (a0 + a1) + (a2 + a3));
}

// K3: E/S reduce -> inv; blend; LayerNorm; write out. 1 block, 36 KB of
// reads (partE/partS 4 KB + attn_raw/cur 32 KB) — small tail.
__global__ __launch_bounds__(1024) void finalize_kernel(
    const float* __restrict__ attn_raw, const float* __restrict__ partE,
    const float* __restrict__ partS, const float* __restrict__ cur,
    float* __restrict__ out, int D)
{
    __shared__ float sh[16];
    const int tid = threadIdx.x;

    float E = 0.0f, S = 0.0f;
    for (int i = tid; i < NB; i += 1024) { E += partE[i]; S += partS[i]; }
    E = block_sum(E, sh, 16);
    S = block_sum(S, sh, 16);
    const float inv = 1.0f / (S + 1e-9f * E);

    float v[4];
    float s = 0.0f, s2 = 0.0f;
#pragma unroll
    for (int k = 0; k < 4; ++k) {
        const int c = tid + k * 1024;
        const float nv = ALPHA * cur[c] + (1.0f - ALPHA) * (attn_raw[c] * inv);
        v[k] = nv;
        s += nv; s2 += nv * nv;
    }
    s = block_sum(s, sh, 16);
    s2 = block_sum(s2, sh, 16);
    const float mean = s / (float)D;
    const float var = s2 / (float)D - mean * mean;
    const float rstd = 1.0f / sqrtf(var + LN_EPS);
#pragma unroll
    for (int k = 0; k < 4; ++k)
        out[tid + k * 1024] = (v[k] - mean) * rstd;
}

extern "C" void kernel_launch(void* const* d_in, const int* in_sizes, int n_in,
                              void* d_out, int out_size, void* d_ws, size_t ws_size,
                              hipStream_t stream) {
    const float* states     = (const float*)d_in[0];
    const float* weights    = (const float*)d_in[1];
    const float* timestamps = (const float*)d_in[2];
    const float* current    = (const float*)d_in[3];
    // d_in[4] = sensed_state: not used in the output math.
    const float* t_new      = (const float*)d_in[5];
    float* out = (float*)d_out;

    const int M = in_sizes[1];   // 8192
    const int D = in_sizes[3];   // 4096

    float* ws       = (float*)d_ws;
    float* partial  = ws;                              // [NB * D] (8 MiB)
    float* partE    = partial + (size_t)NB * D;        // [NB]
    float* partS    = partE + NB;                      // [NB]
    float* attn_raw = partS + NB;                      // [D]

    const float scale = 1.0f / sqrtf((float)D);

    // Zero the atomic accumulator (graph-capturable async memset).
    hipMemsetAsync(attn_raw, 0, (size_t)D * sizeof(float), stream);

    fused_kernel<<<NB, 512, 0, stream>>>(
        states, current, weights, timestamps, t_new,
        partial, partE, partS, M, D, scale);

    {
        dim3 grid(D / 256, K2Y);   // (16, 32)
        reduce_kernel<<<grid, 256, 0, stream>>>(partial, attn_raw, D);
    }

    finalize_kernel<<<1, 1024, 0, stream>>>(attn_raw, partE, partS, current, out, D);
}

// Round 10
// 37.544 us; speedup vs baseline: 1.8948x; 1.0549x over previous
//
#include <hip/hip_runtime.h>
#include <math.h>

#define LAMBDA_DECAY 0.01f
#define ALPHA 0.95f
#define LN_EPS 1e-5f

// Geometry (reference: M=8192, D=4096).
#define NB 512       // K1 blocks
#define RPB 16       // rows per block = M/NB
#define WPB 8        // waves per block (512 threads); wave owns D/8 = 512 cols
#define BATCH 2      // rows per barrier in K1
#define NBATCH 8     // RPB/BATCH
#define G2 64        // partials per K2 block
#define NP2 8        // NB/G2

typedef float v4f __attribute__((ext_vector_type(4)));

static __device__ __forceinline__ float wave_sum_all(float v) {
#pragma unroll
    for (int o = 32; o > 0; o >>= 1) v += __shfl_xor(v, o);
    return v;
}

static __device__ float block_sum(float v, float* sh, int nwaves) {
    int lane = threadIdx.x & 63;
    int w = threadIdx.x >> 6;
    v = wave_sum_all(v);
    if (lane == 0) sh[w] = v;
    __syncthreads();
    float r = 0.0f;
    for (int i = 0; i < nwaves; ++i) r += sh[i];
    __syncthreads();
    return r;
}

// K1: single pass over states. 8 waves/block; wave owns a 512-float D-slice
// (2 float4/lane). R6 structure with TWO rows per barrier (BATCH=2):
//   prefetch next 2 rows (4 loads/lane in flight) -> 2 partial dots ->
//   lane0 writes 2 floats to double-buffered LDS -> ONE __syncthreads ->
//   broadcast-read -> 2 exp -> 2 acc updates.
// Barriers: 16 -> 8 per block. No launch-bounds VGPR cap (R7's mistake),
// no nontemporal. Decayed weights for all 16 rows precomputed at start so
// no latency-exposed loads sit in the post-barrier critical path.
// Race-safety: shp double-buffered; one barrier per batch is sufficient.
__global__ __launch_bounds__(512) void fused_kernel(
    const float* __restrict__ states, const float* __restrict__ cur,
    const float* __restrict__ weights, const float* __restrict__ ts,
    const float* __restrict__ t_new,
    float* __restrict__ partial, float* __restrict__ partE, float* __restrict__ partS,
    int M, int D, float scale)
{
    __shared__ float shp[2][BATCH][WPB];

    const int wid = threadIdx.x >> 6;
    const int lane = threadIdx.x & 63;
    const int r0 = blockIdx.x * RPB;
    const int f4base = wid * 128 + lane;     // float4 index of lane's first elem
    const int rstride = D >> 2;              // row stride in float4 (1024)

    const float tn = t_new[0];

    const v4f* c4 = (const v4f*)cur;
    const v4f curp0 = c4[f4base];
    const v4f curp1 = c4[f4base + 64];

    // Precompute decayed weights for this block's rows (static indexing).
    float wdec[RPB];
#pragma unroll
    for (int r = 0; r < RPB; ++r)
        wdec[r] = weights[r0 + r] * expf(-LAMBDA_DECAY * fabsf(tn - ts[r0 + r]));

    v4f acc0 = (v4f)(0.0f), acc1 = (v4f)(0.0f);
    float E = 0.0f, S = 0.0f;

    const v4f* sp = (const v4f*)states + (size_t)r0 * rstride + f4base;

    v4f rv[2][BATCH][2];
#pragma unroll
    for (int k = 0; k < BATCH; ++k) {
        rv[0][k][0] = sp[(size_t)k * rstride];
        rv[0][k][1] = sp[(size_t)k * rstride + 64];
    }

#pragma unroll
    for (int b = 0; b < NBATCH; ++b) {
        const int cb = b & 1;        // compile-time after full unroll
        const int nbuf = cb ^ 1;

        // Prefetch next batch: 4 loads/lane in flight under this batch.
        if (b + 1 < NBATCH) {
#pragma unroll
            for (int k = 0; k < BATCH; ++k) {
                const size_t off = (size_t)((b + 1) * BATCH + k) * rstride;
                rv[nbuf][k][0] = sp[off];
                rv[nbuf][k][1] = sp[off + 64];
            }
        }

        // Partial dots for the 2 current rows (independent chains).
        float pd[BATCH];
#pragma unroll
        for (int k = 0; k < BATCH; ++k) {
            const v4f a0 = rv[cb][k][0], a1 = rv[cb][k][1];
            float d0 = 0.0f, d1 = 0.0f;
            d0 = fmaf(a0[0], curp0[0], d0); d1 = fmaf(a1[0], curp1[0], d1);
            d0 = fmaf(a0[1], curp0[1], d0); d1 = fmaf(a1[1], curp1[1], d1);
            d0 = fmaf(a0[2], curp0[2], d0); d1 = fmaf(a1[2], curp1[2], d1);
            d0 = fmaf(a0[3], curp0[3], d0); d1 = fmaf(a1[3], curp1[3], d1);
            pd[k] = wave_sum_all(d0 + d1);
        }

        if (lane == 0) {
#pragma unroll
            for (int k = 0; k < BATCH; ++k) shp[cb][k][wid] = pd[k];
        }
        __syncthreads();

#pragma unroll
        for (int k = 0; k < BATCH; ++k) {
            float s = 0.0f;
#pragma unroll
            for (int w = 0; w < WPB; ++w) s += shp[cb][k][w];  // broadcast reads
            s *= scale;

            const float e = expf(s);
            const float p = e * wdec[b * BATCH + k];
            E += e; S += p;                   // uniform across threads

            acc0 += p * rv[cb][k][0];
            acc1 += p * rv[cb][k][1];
        }
    }

    v4f* pb = (v4f*)(partial + (size_t)blockIdx.x * D);
    pb[f4base] = acc0;
    pb[f4base + 64] = acc1;
    if (threadIdx.x == 0) {
        partE[blockIdx.x] = E;
        partS[blockIdx.x] = S;
    }
}

// K2: tree-reduce partials NB -> NP2 per column. grid=(D/256, NP2).
__global__ __launch_bounds__(256) void reduce_kernel(
    const float* __restrict__ partial, float* __restrict__ partial2, int D)
{
    const int col = blockIdx.x * 256 + threadIdx.x;
    const int b0 = blockIdx.y * G2;
    float a0 = 0.0f, a1 = 0.0f, a2 = 0.0f, a3 = 0.0f;
    for (int b = 0; b < G2; b += 4) {
        a0 += partial[(size_t)(b0 + b) * D + col];
        a1 += partial[(size_t)(b0 + b + 1) * D + col];
        a2 += partial[(size_t)(b0 + b + 2) * D + col];
        a3 += partial[(size_t)(b0 + b + 3) * D + col];
    }
    partial2[(size_t)blockIdx.y * D + col] = (a0 + a1) + (a2 + a3);
}

// K3: final NP2-way column sum + E/S reduce -> inv; blend; LayerNorm. 1 block.
__global__ __launch_bounds__(1024) void finalize_kernel(
    const float* __restrict__ partial2, const float* __restrict__ partE,
    const float* __restrict__ partS, const float* __restrict__ cur,
    float* __restrict__ out, int D)
{
    __shared__ float sh[16];
    const int tid = threadIdx.x;

    float E = 0.0f, S = 0.0f;
    for (int i = tid; i < NB; i += 1024) { E += partE[i]; S += partS[i]; }
    E = block_sum(E, sh, 16);
    S = block_sum(S, sh, 16);
    const float inv = 1.0f / (S + 1e-9f * E);

    float v[4];
    float s = 0.0f, s2 = 0.0f;
#pragma unroll
    for (int k = 0; k < 4; ++k) {
        const int c = tid + k * 1024;
        float a = 0.0f;
#pragma unroll
        for (int y = 0; y < NP2; ++y) a += partial2[y * D + c];
        const float nv = ALPHA * cur[c] + (1.0f - ALPHA) * (a * inv);
        v[k] = nv;
        s += nv; s2 += nv * nv;
    }
    s = block_sum(s, sh, 16);
    s2 = block_sum(s2, sh, 16);
    const float mean = s / (float)D;
    const float var = s2 / (float)D - mean * mean;
    const float rstd = 1.0f / sqrtf(var + LN_EPS);
#pragma unroll
    for (int k = 0; k < 4; ++k)
        out[tid + k * 1024] = (v[k] - mean) * rstd;
}

extern "C" void kernel_launch(void* const* d_in, const int* in_sizes, int n_in,
                              void* d_out, int out_size, void* d_ws, size_t ws_size,
                              hipStream_t stream) {
    const float* states     = (const float*)d_in[0];
    const float* weights    = (const float*)d_in[1];
    const float* timestamps = (const float*)d_in[2];
    const float* current    = (const float*)d_in[3];
    // d_in[4] = sensed_state: not used in the output math.
    const float* t_new      = (const float*)d_in[5];
    float* out = (float*)d_out;

    const int M = in_sizes[1];   // 8192
    const int D = in_sizes[3];   // 4096

    float* ws       = (float*)d_ws;
    float* partial  = ws;                              // [NB * D] (8 MiB)
    float* partial2 = partial + (size_t)NB * D;        // [NP2 * D]
    float* partE    = partial2 + (size_t)NP2 * D;      // [NB]
    float* partS    = partE + NB;                      // [NB]

    const float scale = 1.0f / sqrtf((float)D);

    fused_kernel<<<NB, 512, 0, stream>>>(
        states, current, weights, timestamps, t_new,
        partial, partE, partS, M, D, scale);

    {
        dim3 grid(D / 256, NP2);   // (16, 8)
        reduce_kernel<<<grid, 256, 0, stream>>>(partial, partial2, D);
    }

    finalize_kernel<<<1, 1024, 0, stream>>>(partial2, partE, partS, current, out, D);
}